// Round 10
// baseline (216.627 us; speedup 1.0000x reference)
//
#include <hip/hip_runtime.h>
#include <math.h>

#define H_BINS 61
#define HB2 (H_BINS * H_BINS)       // 3721
#define SLOTS (3 * HB2)             // 11163
#define NPIX 22500                  // 150*150
#define NIMG 64
#define Q_PER_IMG 5625              // float4 quads per image
#define NQ (NIMG * Q_PER_IMG)       // 360000
#define OUT_ELEMS (NIMG * SLOTS)

#define REP 8                       // histogram replicas per image (hot-bin spread)
#define HSTRIDE 11264               // floats per replica (SLOTS padded, /256)
#define IMG_STRIDE (REP * HSTRIDE)  // 90112 floats per image
#define HIST_FLOATS (NIMG * IMG_STRIDE)  // 5,767,168 floats = 23.07 MB

#define EPSF 2.2204e-16f
#define HALFW ((float)(6.4 / 61.0 / 2.0))

// A[h] = -3.2f + h*delta, all f32 rn ops (mirrors linspace in f32; rn blocks FMA)
__device__ __forceinline__ float bin_center(int h) {
    const float delta = __fdiv_rn(__fsub_rn(3.0951f, -3.2f), 60.0f);
    return __fadd_rn(-3.2f, __fmul_rn((float)h, delta));
}

// Exact-predicate bin lookup, 2 candidates, branchless, array-free (R7/R8).
__device__ __forceinline__ int find_bin(float t) {
    const float inv_delta = 60.0f / 6.2951f;   // estimate only
    int k = (int)floorf(__fmul_rn(__fadd_rn(t, 3.2f), inv_delta));
    int best = -1;
    #pragma unroll
    for (int dh = 0; dh <= 1; ++dh) {
        int h = k + dh;
        bool in_rng = ((unsigned)h < (unsigned)H_BINS);
        bool hit = (fabsf(__fsub_rn(t, bin_center(h))) <= HALFW);
        best = (in_rng && hit) ? h : best;
    }
    return best;
}

// Per-pixel: identical arithmetic to all passing rounds; atomics go to the
// lane's GLOBAL replica (routes around the lane-serialized LDS atomic unit).
#define PIX(r, g, bl)                                                         \
    {                                                                         \
        float iy = __fsqrt_rn(__fadd_rn(                                      \
            __fadd_rn(__fmul_rn(r, r), __fmul_rn(g, g)), __fmul_rn(bl, bl))); \
        float l0 = logf(__fadd_rn(fabsf(r),  EPSF));                          \
        float l1 = logf(__fadd_rn(fabsf(g),  EPSF));                          \
        float l2 = logf(__fadd_rn(fabsf(bl), EPSF));                          \
        int u0 = find_bin(__fsub_rn(l0, l1));                                 \
        int v0 = find_bin(__fsub_rn(l0, l2));                                 \
        int u1 = find_bin(__fsub_rn(l1, l0));                                 \
        int v1 = find_bin(__fsub_rn(l1, l2));                                 \
        int u2 = find_bin(__fsub_rn(l2, l0));                                 \
        int v2 = find_bin(__fsub_rn(l2, l1));                                 \
        if (u0 >= 0 && v0 >= 0)                                               \
            unsafeAtomicAdd(hb + (u0 * H_BINS + v0), iy);                     \
        if (u1 >= 0 && v1 >= 0)                                               \
            unsafeAtomicAdd(hb + (HB2 + u1 * H_BINS + v1), iy);               \
        if (u2 >= 0 && v2 >= 0)                                               \
            unsafeAtomicAdd(hb + (2 * HB2 + u2 * H_BINS + v2), iy);           \
    }

__global__ __launch_bounds__(256) void zero_ws(float4* __restrict__ p, int n4) {
    int i = blockIdx.x * 256 + threadIdx.x;
    if (i < n4) p[i] = make_float4(0.f, 0.f, 0.f, 0.f);
}

// Fused streaming kernel: no LDS, full occupancy, global atomics to replicas.
__global__ __launch_bounds__(256) void hist_glob(const float* __restrict__ X,
                                                 float* __restrict__ hist) {
    int q = blockIdx.x * 256 + threadIdx.x;
    if (q >= NQ) return;
    int b  = q / Q_PER_IMG;
    int qq = q - b * Q_PER_IMG;
    const float* base = X + (size_t)b * 3 * NPIX + 4 * qq;
    float4 r4 = *(const float4*)base;
    float4 g4 = *(const float4*)(base + NPIX);
    float4 b4 = *(const float4*)(base + 2 * NPIX);

    // lane&7 picks the replica: a wave's hot-bin traffic spreads over 8 addrs
    float* hb = hist + (size_t)b * IMG_STRIDE
                     + (size_t)(threadIdx.x & (REP - 1)) * HSTRIDE;
    PIX(r4.x, g4.x, b4.x)
    PIX(r4.y, g4.y, b4.y)
    PIX(r4.z, g4.z, b4.z)
    PIX(r4.w, g4.w, b4.w)
}

// out = sqrt(sum of 8 replicas) * C[ch]/N
__global__ __launch_bounds__(256) void finalize(const float* __restrict__ hist,
                                                const float* __restrict__ C,
                                                float* __restrict__ out) {
    int idx = blockIdx.x * 256 + threadIdx.x;
    if (idx >= OUT_ELEMS) return;
    int b  = idx / SLOTS;
    int j  = idx - b * SLOTS;
    int ch = j / HB2;
    const float* hb = hist + (size_t)b * IMG_STRIDE + j;
    float s = hb[0];
    #pragma unroll
    for (int r = 1; r < REP; ++r) s = __fadd_rn(s, hb[(size_t)r * HSTRIDE]);
    float scale = __fdiv_rn(C[ch], 22500.0f);   // C[i]/N in f32, as reference
    out[idx] = __fmul_rn(__fsqrt_rn(s), scale);
}

// ---- tiny-ws fallback (not taken with 256MB ws): LDS-hist path ----
#define DO_PAIR(P, IU, IV)                                                   \
    {                                                                        \
        int bu_ = find_bin(IU);                                              \
        int bv_ = find_bin(IV);                                              \
        if (bu_ >= 0 && bv_ >= 0)                                            \
            unsafeAtomicAdd(&hflat[(P) * HB2 + bu_ * H_BINS + bv_], iy);     \
    }
#define DO_PIXEL(r, g, bl)                                                   \
    {                                                                        \
        float iy = __fsqrt_rn(__fadd_rn(                                     \
            __fadd_rn(__fmul_rn(r, r), __fmul_rn(g, g)), __fmul_rn(bl, bl)));\
        float l0 = logf(__fadd_rn(fabsf(r),  EPSF));                         \
        float l1 = logf(__fadd_rn(fabsf(g),  EPSF));                         \
        float l2 = logf(__fadd_rn(fabsf(bl), EPSF));                         \
        DO_PAIR(0, __fsub_rn(l0, l1), __fsub_rn(l0, l2))                     \
        DO_PAIR(1, __fsub_rn(l1, l0), __fsub_rn(l1, l2))                     \
        DO_PAIR(2, __fsub_rn(l2, l0), __fsub_rn(l2, l1))                     \
    }
__global__ __launch_bounds__(256) void zero_out(float4* __restrict__ o, int n4) {
    int i = blockIdx.x * 256 + threadIdx.x;
    if (i < n4) o[i] = make_float4(0.f, 0.f, 0.f, 0.f);
}
__global__ __launch_bounds__(512) void hist_atomic(const float* __restrict__ X,
                                                   float* __restrict__ out) {
    __shared__ float hflat[SLOTS];
    const int chunk = blockIdx.x % 12;
    const int b     = blockIdx.x / 12;
    for (int i = threadIdx.x; i < SLOTS; i += 512) hflat[i] = 0.0f;
    __syncthreads();
    const float* Xb = X + (size_t)b * 3 * NPIX;
    const int ppc = NPIX / 12;
    for (int n = chunk * ppc + threadIdx.x; n < (chunk + 1) * ppc; n += 512) {
        float r = Xb[n], g = Xb[NPIX + n], bl = Xb[2 * NPIX + n];
        DO_PIXEL(r, g, bl)
    }
    __syncthreads();
    float* ob = out + (size_t)b * SLOTS;
    for (int i = threadIdx.x; i < SLOTS; i += 512) {
        float v = hflat[i];
        if (v != 0.0f) unsafeAtomicAdd(&ob[i], v);
    }
}
__global__ __launch_bounds__(256) void finalize_inplace(float* __restrict__ out,
                                                        const float* __restrict__ C) {
    int idx = blockIdx.x * 256 + threadIdx.x;
    if (idx >= OUT_ELEMS) return;
    int ch = (idx / HB2) % 3;
    float scale = __fdiv_rn(C[ch], 22500.0f);
    out[idx] = __fmul_rn(__fsqrt_rn(out[idx]), scale);
}

extern "C" void kernel_launch(void* const* d_in, const int* in_sizes, int n_in,
                              void* d_out, int out_size, void* d_ws, size_t ws_size,
                              hipStream_t stream) {
    const float* X = (const float*)d_in[0];
    const float* C = (const float*)d_in[1];
    float* out = (float*)d_out;

    const size_t need = (size_t)HIST_FLOATS * sizeof(float);   // 23.07 MB
    if (ws_size >= need) {
        float* hist = (float*)d_ws;
        int n4 = HIST_FLOATS / 4;                              // 1,441,792
        zero_ws<<<(n4 + 255) / 256, 256, 0, stream>>>((float4*)hist, n4);
        hist_glob<<<(NQ + 255) / 256, 256, 0, stream>>>(X, hist);
        finalize<<<(OUT_ELEMS + 255) / 256, 256, 0, stream>>>(hist, C, out);
    } else {
        int n4 = OUT_ELEMS / 4;
        zero_out<<<(n4 + 255) / 256, 256, 0, stream>>>((float4*)out, n4);
        hist_atomic<<<NIMG * 12, 512, 0, stream>>>(X, out);
        finalize_inplace<<<(OUT_ELEMS + 255) / 256, 256, 0, stream>>>(out, C);
    }
}

// Round 11
// 38.765 us; speedup vs baseline: 5.5882x; 5.5882x over previous
//
#include <hip/hip_runtime.h>
#include <math.h>

#define H_BINS 61
#define HB2 (H_BINS * H_BINS)       // 3721
#define SLOTS (3 * HB2)             // 11163
#define NPIX 22500                  // 150*150
#define NIMG 64
#define OUT_ELEMS (NIMG * SLOTS)

#define REP 4                       // LDS replicas per pair-histogram
#define NCH 4                       // chunks per (img,pair)
#define PPC (NPIX / NCH)            // 5625 pixels per chunk
#define NT 512
#define PSTRIDE 3728                // padded partial stride (floats, 16B mult)
#define NPART (NIMG * 3 * NCH)      // 768 partials

#define EPSF 2.2204e-16f
#define HALFW ((float)(6.4 / 61.0 / 2.0))

// A[h] = -3.2f + h*delta, all f32 rn ops (mirrors linspace in f32; rn blocks FMA)
__device__ __forceinline__ float bin_center(int h) {
    const float delta = __fdiv_rn(__fsub_rn(3.0951f, -3.2f), 60.0f);
    return __fadd_rn(-3.2f, __fmul_rn((float)h, delta));
}

// Exact-predicate bin lookup, 2 candidates, branchless, array-free (R7/R8).
__device__ __forceinline__ int find_bin(float t) {
    const float inv_delta = 60.0f / 6.2951f;   // estimate only
    int k = (int)floorf(__fmul_rn(__fadd_rn(t, 3.2f), inv_delta));
    int best = -1;
    #pragma unroll
    for (int dh = 0; dh <= 1; ++dh) {
        int h = k + dh;
        bool in_rng = ((unsigned)h < (unsigned)H_BINS);
        bool hit = (fabsf(__fsub_rn(t, bin_center(h))) <= HALFW);
        best = (in_rng && hit) ? h : best;
    }
    return best;
}

// One block = (image, pair, quarter-chunk). 4 LDS replicas; lane&3 selects.
// Replica stride 3721 words = bank shift 9 => cross-replica traffic also
// lands in different banks. Same-address wave multiplicity drops ~4x.
__global__ __launch_bounds__(NT) void hist_rep(const float* __restrict__ X,
                                               float* __restrict__ partials) {
    __shared__ float hist[REP * HB2];          // 59,536 B -> 2 blocks/CU
    const int bid = blockIdx.x;
    const int c   = bid & (NCH - 1);
    const int bp  = bid >> 2;                  // (b*3 + p)
    const int p   = bp % 3;
    const int b   = bp / 3;

    for (int i = threadIdx.x; i < REP * HB2; i += NT) hist[i] = 0.0f;
    __syncthreads();

    const float* Xb = X + (size_t)b * 3 * NPIX;
    const int n0 = c * PPC;
    const int n1 = n0 + PPC;
    float* hrep = hist + (threadIdx.x & (REP - 1)) * HB2;

    for (int n = n0 + threadIdx.x; n < n1; n += NT) {
        float r  = Xb[n];
        float g  = Xb[NPIX + n];
        float bl = Xb[2 * NPIX + n];

        // identical ops to all passing rounds
        float iy = __fsqrt_rn(__fadd_rn(
            __fadd_rn(__fmul_rn(r, r), __fmul_rn(g, g)), __fmul_rn(bl, bl)));
        float l0 = logf(__fadd_rn(fabsf(r),  EPSF));
        float l1 = logf(__fadd_rn(fabsf(g),  EPSF));
        float l2 = logf(__fadd_rn(fabsf(bl), EPSF));

        float iu, iv;                          // wave-uniform branch (p per block)
        if (p == 0)      { iu = __fsub_rn(l0, l1); iv = __fsub_rn(l0, l2); }
        else if (p == 1) { iu = __fsub_rn(l1, l0); iv = __fsub_rn(l1, l2); }
        else             { iu = __fsub_rn(l2, l0); iv = __fsub_rn(l2, l1); }

        int u = find_bin(iu);
        int v = find_bin(iv);
        if (u >= 0 && v >= 0)
            unsafeAtomicAdd(hrep + (u * H_BINS + v), iy);   // ds_add_f32
    }
    __syncthreads();

    // merge 4 replicas + flush one partial (plain coalesced stores)
    float* dst = partials + (size_t)bid * PSTRIDE;
    for (int j = threadIdx.x; j < HB2; j += NT) {
        float s = __fadd_rn(__fadd_rn(__fadd_rn(hist[j], hist[HB2 + j]),
                                      hist[2 * HB2 + j]), hist[3 * HB2 + j]);
        dst[j] = s;
    }
}

// One block per (img,pair): sum 4 chunk-partials, sqrt*C/N, write out.
__global__ __launch_bounds__(256) void reduce2(const float* __restrict__ partials,
                                               const float* __restrict__ C,
                                               float* __restrict__ out) {
    const int bp = blockIdx.x;                 // (b*3 + p)
    const int p  = bp % 3;
    const int b  = bp / 3;
    float scale = __fdiv_rn(C[p], 22500.0f);   // C[i]/N in f32
    const float* base = partials + (size_t)bp * NCH * PSTRIDE;
    float* ob = out + (size_t)b * SLOTS + p * HB2;
    for (int j = threadIdx.x; j < HB2; j += 256) {
        float s = __fadd_rn(__fadd_rn(__fadd_rn(base[j], base[PSTRIDE + j]),
                                      base[2 * PSTRIDE + j]), base[3 * PSTRIDE + j]);
        ob[j] = __fmul_rn(__fsqrt_rn(s), scale);
    }
}

// ---- tiny-ws fallback (not taken with 256MB ws): single-hist LDS path ----
#define DO_PAIR(P, IU, IV)                                                   \
    {                                                                        \
        int bu_ = find_bin(IU);                                              \
        int bv_ = find_bin(IV);                                              \
        if (bu_ >= 0 && bv_ >= 0)                                            \
            unsafeAtomicAdd(&hflat[(P) * HB2 + bu_ * H_BINS + bv_], iy);     \
    }
#define DO_PIXEL(r, g, bl)                                                   \
    {                                                                        \
        float iy = __fsqrt_rn(__fadd_rn(                                     \
            __fadd_rn(__fmul_rn(r, r), __fmul_rn(g, g)), __fmul_rn(bl, bl)));\
        float l0 = logf(__fadd_rn(fabsf(r),  EPSF));                         \
        float l1 = logf(__fadd_rn(fabsf(g),  EPSF));                         \
        float l2 = logf(__fadd_rn(fabsf(bl), EPSF));                         \
        DO_PAIR(0, __fsub_rn(l0, l1), __fsub_rn(l0, l2))                     \
        DO_PAIR(1, __fsub_rn(l1, l0), __fsub_rn(l1, l2))                     \
        DO_PAIR(2, __fsub_rn(l2, l0), __fsub_rn(l2, l1))                     \
    }
__global__ __launch_bounds__(256) void zero_out(float4* __restrict__ o, int n4) {
    int i = blockIdx.x * 256 + threadIdx.x;
    if (i < n4) o[i] = make_float4(0.f, 0.f, 0.f, 0.f);
}
__global__ __launch_bounds__(512) void hist_atomic(const float* __restrict__ X,
                                                   float* __restrict__ out) {
    __shared__ float hflat[SLOTS];
    const int chunk = blockIdx.x % 12;
    const int b     = blockIdx.x / 12;
    for (int i = threadIdx.x; i < SLOTS; i += 512) hflat[i] = 0.0f;
    __syncthreads();
    const float* Xb = X + (size_t)b * 3 * NPIX;
    const int ppc = NPIX / 12;
    for (int n = chunk * ppc + threadIdx.x; n < (chunk + 1) * ppc; n += 512) {
        float r = Xb[n], g = Xb[NPIX + n], bl = Xb[2 * NPIX + n];
        DO_PIXEL(r, g, bl)
    }
    __syncthreads();
    float* ob = out + (size_t)b * SLOTS;
    for (int i = threadIdx.x; i < SLOTS; i += 512) {
        float v = hflat[i];
        if (v != 0.0f) unsafeAtomicAdd(&ob[i], v);
    }
}
__global__ __launch_bounds__(256) void finalize_inplace(float* __restrict__ out,
                                                        const float* __restrict__ C) {
    int idx = blockIdx.x * 256 + threadIdx.x;
    if (idx >= OUT_ELEMS) return;
    int ch = (idx / HB2) % 3;
    float scale = __fdiv_rn(C[ch], 22500.0f);
    out[idx] = __fmul_rn(__fsqrt_rn(out[idx]), scale);
}

extern "C" void kernel_launch(void* const* d_in, const int* in_sizes, int n_in,
                              void* d_out, int out_size, void* d_ws, size_t ws_size,
                              hipStream_t stream) {
    const float* X = (const float*)d_in[0];
    const float* C = (const float*)d_in[1];
    float* out = (float*)d_out;

    const size_t need = (size_t)NPART * PSTRIDE * sizeof(float);   // ~11.4 MB
    if (ws_size >= need) {
        float* partials = (float*)d_ws;
        hist_rep<<<NPART, NT, 0, stream>>>(X, partials);
        reduce2<<<NIMG * 3, 256, 0, stream>>>(partials, C, out);
    } else {
        int n4 = OUT_ELEMS / 4;
        zero_out<<<(n4 + 255) / 256, 256, 0, stream>>>((float4*)out, n4);
        hist_atomic<<<NIMG * 12, 512, 0, stream>>>(X, out);
        finalize_inplace<<<(OUT_ELEMS + 255) / 256, 256, 0, stream>>>(out, C);
    }
}

// Round 12
// 31.834 us; speedup vs baseline: 6.8049x; 1.2177x over previous
//
#include <hip/hip_runtime.h>
#include <math.h>

#define H_BINS 61
#define HB2 (H_BINS * H_BINS)       // 3721
#define SLOTS (3 * HB2)             // 11163
#define NPIX 22500                  // 150*150
#define NIMG 64
#define OUT_ELEMS (NIMG * SLOTS)

#define REP 4                       // LDS replicas per pair-histogram
#define NCH 4                       // chunks per (img,pair)
#define PPC (NPIX / NCH)            // 5625 pixels per chunk
#define NT 512
#define PSTRIDE 3728                // padded partial stride (u32 words)
#define NPART (NIMG * 3 * NCH)      // 768 partials

#define EPSF 2.2204e-16f
#define HALFW ((float)(6.4 / 61.0 / 2.0))
#define FXSCALE 1048576.0f          // 2^20 fixed-point scale
#define FXINV   (1.0f / 1048576.0f)

// A[h] = -3.2f + h*delta, all f32 rn ops (mirrors linspace in f32; rn blocks FMA)
__device__ __forceinline__ float bin_center(int h) {
    const float delta = __fdiv_rn(__fsub_rn(3.0951f, -3.2f), 60.0f);
    return __fadd_rn(-3.2f, __fmul_rn((float)h, delta));
}

// Exact-predicate bin lookup, 2 candidates, branchless, array-free (R7/R8).
__device__ __forceinline__ int find_bin(float t) {
    const float inv_delta = 60.0f / 6.2951f;   // estimate only
    int k = (int)floorf(__fmul_rn(__fadd_rn(t, 3.2f), inv_delta));
    int best = -1;
    #pragma unroll
    for (int dh = 0; dh <= 1; ++dh) {
        int h = k + dh;
        bool in_rng = ((unsigned)h < (unsigned)H_BINS);
        bool hit = (fabsf(__fsub_rn(t, bin_center(h))) <= HALFW);
        best = (in_rng && hit) ? h : best;
    }
    return best;
}

// One block = (image, pair, quarter-chunk). 4 LDS replicas; lane&3 selects.
// SINGLE CHANGE vs R11: u32 fixed-point ds_add_u32 instead of ds_add_f32
// (hypothesis: LDS FP-RMW is the multi-cycle wall; integer RMW is 1-cycle).
__global__ __launch_bounds__(NT) void hist_rep(const float* __restrict__ X,
                                               unsigned* __restrict__ partials) {
    __shared__ unsigned hist[REP * HB2];       // 59,536 B -> 2 blocks/CU
    const int bid = blockIdx.x;
    const int c   = bid & (NCH - 1);
    const int bp  = bid >> 2;                  // (b*3 + p)
    const int p   = bp % 3;
    const int b   = bp / 3;

    for (int i = threadIdx.x; i < REP * HB2; i += NT) hist[i] = 0u;
    __syncthreads();

    const float* Xb = X + (size_t)b * 3 * NPIX;
    const int n0 = c * PPC;
    const int n1 = n0 + PPC;
    unsigned* hrep = hist + (threadIdx.x & (REP - 1)) * HB2;

    for (int n = n0 + threadIdx.x; n < n1; n += NT) {
        float r  = Xb[n];
        float g  = Xb[NPIX + n];
        float bl = Xb[2 * NPIX + n];

        // identical per-pixel arithmetic to all passing rounds
        float iy = __fsqrt_rn(__fadd_rn(
            __fadd_rn(__fmul_rn(r, r), __fmul_rn(g, g)), __fmul_rn(bl, bl)));
        float l0 = logf(__fadd_rn(fabsf(r),  EPSF));
        float l1 = logf(__fadd_rn(fabsf(g),  EPSF));
        float l2 = logf(__fadd_rn(fabsf(bl), EPSF));

        float iu, iv;                          // wave-uniform branch (p per block)
        if (p == 0)      { iu = __fsub_rn(l0, l1); iv = __fsub_rn(l0, l2); }
        else if (p == 1) { iu = __fsub_rn(l1, l0); iv = __fsub_rn(l1, l2); }
        else             { iu = __fsub_rn(l2, l0); iv = __fsub_rn(l2, l1); }

        int u = find_bin(iu);
        int v = find_bin(iv);
        if (u >= 0 && v >= 0) {
            // fixed-point: round-to-nearest via +0.5 truncate; iy<=1.74 => fits
            unsigned q = (unsigned)(__fmul_rn(iy, FXSCALE) + 0.5f);
            atomicAdd(hrep + (u * H_BINS + v), q);   // native ds_add_u32
        }
    }
    __syncthreads();

    // merge 4 replicas (EXACT integer adds) + flush one partial
    unsigned* dst = partials + (size_t)bid * PSTRIDE;
    for (int j = threadIdx.x; j < HB2; j += NT) {
        unsigned s = hist[j] + hist[HB2 + j] + hist[2 * HB2 + j] + hist[3 * HB2 + j];
        dst[j] = s;
    }
}

// One block per (img,pair): sum 4 chunk-partials (exact u32), convert once,
// sqrt*C/N, write out.
__global__ __launch_bounds__(256) void reduce2(const unsigned* __restrict__ partials,
                                               const float* __restrict__ C,
                                               float* __restrict__ out) {
    const int bp = blockIdx.x;                 // (b*3 + p)
    const int p  = bp % 3;
    const int b  = bp / 3;
    float scale = __fdiv_rn(C[p], 22500.0f);   // C[i]/N in f32
    const unsigned* base = partials + (size_t)bp * NCH * PSTRIDE;
    float* ob = out + (size_t)b * SLOTS + p * HB2;
    for (int j = threadIdx.x; j < HB2; j += 256) {
        unsigned s = base[j] + base[PSTRIDE + j]
                   + base[2 * PSTRIDE + j] + base[3 * PSTRIDE + j];
        float h = __fmul_rn((float)s, FXINV);  // exact pow2 scale
        ob[j] = __fmul_rn(__fsqrt_rn(h), scale);
    }
}

// ---- tiny-ws fallback (not taken with 256MB ws): f32 LDS path (R8-proven) ----
#define DO_PAIR(P, IU, IV)                                                   \
    {                                                                        \
        int bu_ = find_bin(IU);                                              \
        int bv_ = find_bin(IV);                                              \
        if (bu_ >= 0 && bv_ >= 0)                                            \
            unsafeAtomicAdd(&hflat[(P) * HB2 + bu_ * H_BINS + bv_], iy);     \
    }
#define DO_PIXEL(r, g, bl)                                                   \
    {                                                                        \
        float iy = __fsqrt_rn(__fadd_rn(                                     \
            __fadd_rn(__fmul_rn(r, r), __fmul_rn(g, g)), __fmul_rn(bl, bl)));\
        float l0 = logf(__fadd_rn(fabsf(r),  EPSF));                         \
        float l1 = logf(__fadd_rn(fabsf(g),  EPSF));                         \
        float l2 = logf(__fadd_rn(fabsf(bl), EPSF));                         \
        DO_PAIR(0, __fsub_rn(l0, l1), __fsub_rn(l0, l2))                     \
        DO_PAIR(1, __fsub_rn(l1, l0), __fsub_rn(l1, l2))                     \
        DO_PAIR(2, __fsub_rn(l2, l0), __fsub_rn(l2, l1))                     \
    }
__global__ __launch_bounds__(256) void zero_out(float4* __restrict__ o, int n4) {
    int i = blockIdx.x * 256 + threadIdx.x;
    if (i < n4) o[i] = make_float4(0.f, 0.f, 0.f, 0.f);
}
__global__ __launch_bounds__(512) void hist_atomic(const float* __restrict__ X,
                                                   float* __restrict__ out) {
    __shared__ float hflat[SLOTS];
    const int chunk = blockIdx.x % 12;
    const int b     = blockIdx.x / 12;
    for (int i = threadIdx.x; i < SLOTS; i += 512) hflat[i] = 0.0f;
    __syncthreads();
    const float* Xb = X + (size_t)b * 3 * NPIX;
    const int ppc = NPIX / 12;
    for (int n = chunk * ppc + threadIdx.x; n < (chunk + 1) * ppc; n += 512) {
        float r = Xb[n], g = Xb[NPIX + n], bl = Xb[2 * NPIX + n];
        DO_PIXEL(r, g, bl)
    }
    __syncthreads();
    float* ob = out + (size_t)b * SLOTS;
    for (int i = threadIdx.x; i < SLOTS; i += 512) {
        float v = hflat[i];
        if (v != 0.0f) unsafeAtomicAdd(&ob[i], v);
    }
}
__global__ __launch_bounds__(256) void finalize_inplace(float* __restrict__ out,
                                                        const float* __restrict__ C) {
    int idx = blockIdx.x * 256 + threadIdx.x;
    if (idx >= OUT_ELEMS) return;
    int ch = (idx / HB2) % 3;
    float scale = __fdiv_rn(C[ch], 22500.0f);
    out[idx] = __fmul_rn(__fsqrt_rn(out[idx]), scale);
}

extern "C" void kernel_launch(void* const* d_in, const int* in_sizes, int n_in,
                              void* d_out, int out_size, void* d_ws, size_t ws_size,
                              hipStream_t stream) {
    const float* X = (const float*)d_in[0];
    const float* C = (const float*)d_in[1];
    float* out = (float*)d_out;

    const size_t need = (size_t)NPART * PSTRIDE * sizeof(unsigned);   // ~11.4 MB
    if (ws_size >= need) {
        unsigned* partials = (unsigned*)d_ws;
        hist_rep<<<NPART, NT, 0, stream>>>(X, partials);
        reduce2<<<NIMG * 3, 256, 0, stream>>>(partials, C, out);
    } else {
        int n4 = OUT_ELEMS / 4;
        zero_out<<<(n4 + 255) / 256, 256, 0, stream>>>((float4*)out, n4);
        hist_atomic<<<NIMG * 12, 512, 0, stream>>>(X, out);
        finalize_inplace<<<(OUT_ELEMS + 255) / 256, 256, 0, stream>>>(out, C);
    }
}